// Round 2
// baseline (231.035 us; speedup 1.0000x reference)
//
#include <hip/hip_runtime.h>

// FIR 4x4 separable depthwise filter, k1=[1,3,3,1], k2=outer(k1,k1)/64.
// Input x: (8, 64, 512, 512) f32 -> 512 planes of 512x512.
// lax SAME padding for kernel 4: pad_lo=1, pad_hi=2 (zero padding).
// out[r][c] = (1/64) * (H[r-1][c] + 3*H[r][c] + 3*H[r+1][c] + H[r+2][c])
//   H[y][c] = x[y][c-1] + 3*x[y][c] + 3*x[y][c+1] + x[y][c+2]
//
// One wave64 spans a full 512-wide row: 8 floats/lane via 2x dwordx4.
// Column halo (c-1, c+8, c+9) comes from neighbor lanes via shuffles —
// zero extra memory instructions; image edge == wave edge (uniform select).

#define FIR_W 512
#define FIR_H 512
#define FIR_ROWS 64   // rows per wave-strip

struct F8 { float4 a, b; };

__device__ __forceinline__ F8 fir_hrow(const float* __restrict__ p, int y, int lane) {
    F8 h;
    if (y < 0 || y >= FIR_H) {   // y is wave-uniform: branch is non-divergent
        h.a.x = h.a.y = h.a.z = h.a.w = 0.0f;
        h.b = h.a;
        return h;
    }
    const float* row = p + (size_t)y * FIR_W + lane * 8;
    const float4 lo = *reinterpret_cast<const float4*>(row);      // c..c+3
    const float4 hi = *reinterpret_cast<const float4*>(row + 4);  // c+4..c+7

    float xm1 = __shfl_up(hi.w, 1);    // col c-1  (lane-1's elem 7)
    float xp8 = __shfl_down(lo.x, 1);  // col c+8  (lane+1's elem 0)
    float xp9 = __shfl_down(lo.y, 1);  // col c+9  (lane+1's elem 1)
    if (lane == 0)  xm1 = 0.0f;        // left image edge (pad_lo=1)
    if (lane == 63) { xp8 = 0.0f; xp9 = 0.0f; }  // right edge (pad_hi=2)

    h.a.x = xm1  + 3.0f * (lo.x + lo.y) + lo.z;
    h.a.y = lo.x + 3.0f * (lo.y + lo.z) + lo.w;
    h.a.z = lo.y + 3.0f * (lo.z + lo.w) + hi.x;
    h.a.w = lo.z + 3.0f * (lo.w + hi.x) + hi.y;
    h.b.x = lo.w + 3.0f * (hi.x + hi.y) + hi.z;
    h.b.y = hi.x + 3.0f * (hi.y + hi.z) + hi.w;
    h.b.z = hi.y + 3.0f * (hi.z + hi.w) + xp8;
    h.b.w = hi.z + 3.0f * (hi.w + xp8)  + xp9;
    return h;
}

__device__ __forceinline__ float4 fir_vcomb(float4 h0, float4 h1, float4 h2, float4 h3) {
    const float s = 1.0f / 64.0f;
    float4 o;
    o.x = (h0.x + h3.x + 3.0f * (h1.x + h2.x)) * s;
    o.y = (h0.y + h3.y + 3.0f * (h1.y + h2.y)) * s;
    o.z = (h0.z + h3.z + 3.0f * (h1.z + h2.z)) * s;
    o.w = (h0.w + h3.w + 3.0f * (h1.w + h2.w)) * s;
    return o;
}

__global__ __launch_bounds__(256) void FIRFilter_88579405512825_kernel(
        const float* __restrict__ x, float* __restrict__ out) {
    const int lane  = threadIdx.x;                               // 0..63: 8 cols each
    const int strip = blockIdx.x * blockDim.y + threadIdx.y;     // 0..7: 64-row strip
    const int plane = blockIdx.y;                                // 0..511: (b, c) plane

    const float* p = x   + (size_t)plane * (FIR_W * FIR_H);
    float*       q = out + (size_t)plane * (FIR_W * FIR_H);

    const int r0 = strip * FIR_ROWS;

    // Rolling window of horizontal-filtered rows: need H(r-1..r+2) for row r.
    F8 h1 = fir_hrow(p, r0 - 1, lane);
    F8 h2 = fir_hrow(p, r0,     lane);
    F8 h3 = fir_hrow(p, r0 + 1, lane);

    #pragma unroll 4
    for (int r = r0; r < r0 + FIR_ROWS; ++r) {
        F8 h0 = h1; h1 = h2; h2 = h3;
        h3 = fir_hrow(p, r + 2, lane);

        float* qr = q + (size_t)r * FIR_W + lane * 8;
        *reinterpret_cast<float4*>(qr)     = fir_vcomb(h0.a, h1.a, h2.a, h3.a);
        *reinterpret_cast<float4*>(qr + 4) = fir_vcomb(h0.b, h1.b, h2.b, h3.b);
    }
}

extern "C" void kernel_launch(void* const* d_in, const int* in_sizes, int n_in,
                              void* d_out, int out_size, void* d_ws, size_t ws_size,
                              hipStream_t stream) {
    const float* x = (const float*)d_in[0];
    float* out = (float*)d_out;

    const int planes = in_sizes[0] / (FIR_W * FIR_H);   // 8*64 = 512

    // block: 64 lanes (one wave per row-strip) x 4 strips = 256 threads
    dim3 block(64, 4);
    // grid.x: 512 rows / (64 rows * 4 strips) = 2 ; grid.y: planes
    dim3 grid(FIR_H / (FIR_ROWS * 4), planes);

    FIRFilter_88579405512825_kernel<<<grid, block, 0, stream>>>(x, out);
}